// Round 6
// baseline (573.053 us; speedup 1.0000x reference)
//
#include <hip/hip_runtime.h>
#include <hip/hip_bf16.h>

#define E_DIM 1024
#define HEADS 16
#define DHEAD 64
#define RANK 8
#define BATCH 4
#define SEQ 4096
#define MTOT (BATCH*SEQ)
#define LDK 64   // shorts per LDS row (128 B), BK=64

typedef short bf16x8 __attribute__((ext_vector_type(8)));
typedef float f32x4  __attribute__((ext_vector_type(4)));

__device__ __forceinline__ float bf2f(unsigned short u) {
    return __uint_as_float(((unsigned int)u) << 16);
}
__device__ __forceinline__ unsigned short f2bf(float f) {
    unsigned int x = __float_as_uint(f);
    unsigned int r = (x + 0x7fffu + ((x >> 16) & 1u)) >> 16;
    return (unsigned short)r;
}
// pack two f32 -> two bf16 (round-half-up; bias 2^-17, negligible)
__device__ __forceinline__ unsigned int pack2bf(float lo, float hi) {
    unsigned int l = __float_as_uint(lo), h = __float_as_uint(hi);
    return ((h + 0x8000u) & 0xFFFF0000u) | ((l + 0x8000u) >> 16);
}
// async global->LDS, 16 B per lane, wave-uniform LDS base
__device__ __forceinline__ void async16(const void* g, void* l) {
    __builtin_amdgcn_global_load_lds(
        (const __attribute__((address_space(1))) unsigned int*)g,
        (__attribute__((address_space(3))) unsigned int*)l, 16, 0, 0);
}

// ---------------------------------------------------------------------------
// sentinel: report ws_size (MB) through the absmax channel if budget too small
// ---------------------------------------------------------------------------
__global__ __launch_bounds__(256)
void ws_sentinel(float* __restrict__ out, float mb)
{
    out[threadIdx.x] = mb;
}

// ---------------------------------------------------------------------------
// K1: Wt[g][n][k] = bf16( W[g][k][n] + sum_r A[g][k][r] B[g][r][n] )
// ---------------------------------------------------------------------------
__global__ __launch_bounds__(256)
void prep_weights_t(const float* __restrict__ Wq, const float* __restrict__ Wk,
                    const float* __restrict__ Wv, const float* __restrict__ Wo,
                    const float* __restrict__ qa, const float* __restrict__ qb,
                    const float* __restrict__ ka, const float* __restrict__ kb,
                    const float* __restrict__ va, const float* __restrict__ vb,
                    unsigned short* __restrict__ Wt)
{
    __shared__ float tile[32][33];
    const int n0 = blockIdx.x * 32;
    const int k0 = blockIdx.y * 32;
    const int g  = blockIdx.z;
    const float* W = (g==0)?Wq:(g==1)?Wk:(g==2)?Wv:Wo;
    const float* A = (g==0)?qa:(g==1)?ka:va;
    const float* Bm= (g==0)?qb:(g==1)?kb:vb;
    const int t  = threadIdx.x;
    const int r  = t >> 3;
    const int c4 = (t & 7) * 4;

    float4 v = *(const float4*)(W + (size_t)(k0 + r)*E_DIM + n0 + c4);
    float o0=v.x, o1=v.y, o2=v.z, o3=v.w;
    if (g < 3) {
        #pragma unroll
        for (int rr = 0; rr < RANK; ++rr) {
            float av = A[(k0 + r)*RANK + rr];
            const float* bp = Bm + (size_t)rr*E_DIM + n0 + c4;
            o0 = fmaf(av, bp[0], o0);
            o1 = fmaf(av, bp[1], o1);
            o2 = fmaf(av, bp[2], o2);
            o3 = fmaf(av, bp[3], o3);
        }
    }
    tile[r][c4+0]=o0; tile[r][c4+1]=o1; tile[r][c4+2]=o2; tile[r][c4+3]=o3;
    __syncthreads();
    union { unsigned short h[4]; uint2 u; } o;
    #pragma unroll
    for (int i = 0; i < 4; ++i) o.h[i] = f2bf(tile[c4+i][r]);
    *(uint2*)(Wt + (size_t)g*1048576 + (size_t)(n0 + r)*E_DIM + k0 + c4) = o.u;
}

// ---------------------------------------------------------------------------
// K2: MFMA GEMM  C[M,1024] = X[M,1024] @ Wt[1024n,1024k]^T + bias
// 128x128 tile, BK=64, 4 waves (2x2 of 64x64), 16x16x32 bf16 MFMA.
// LDS linear [128][64] bf16, chunk XOR-swizzle (slot = chunk ^ (row&7)):
//  - gload_lds path: linear dest, pre-swizzled GLOBAL source chunk
//  - f32 reg-stage path: swizzled ds_write
//  - reads: same XOR -> 2-way banks (free)
// SMAX: fused per-head softmax over the wave's 64-col span (q only).
// ---------------------------------------------------------------------------
template<int XF32, int SMAX, int OUTF32>
__global__ __launch_bounds__(256)
void mfma_gemm(const void* __restrict__ Xv, const unsigned short* __restrict__ Wt,
               const float* __restrict__ bias, void* __restrict__ outv)
{
    __shared__ __align__(16) unsigned short As[128*LDK];
    __shared__ __align__(16) unsigned short Bs[128*LDK];
    const int tid  = threadIdx.x;
    const int lane = tid & 63;
    const int w    = tid >> 6;
    const int wr   = w >> 1, wc = w & 1;
    const int i0   = blockIdx.x * 128;   // i-panel major: same-XCD j-sharing
    const int j0   = blockIdx.y * 128;
    const int l15  = lane & 15, lg = lane >> 4;

    const int srow8  = lane >> 3;                  // row within 8-row group
    const int schunk = (lane & 7) ^ srow8;         // pre-swizzled source chunk

    f32x4 acc[4][4];
    #pragma unroll
    for (int m = 0; m < 4; ++m)
        #pragma unroll
        for (int n = 0; n < 4; ++n) {
            f32x4 z = {0.f, 0.f, 0.f, 0.f};
            acc[m][n] = z;
        }

    for (int k0 = 0; k0 < E_DIM; k0 += 64) {
        // ---- stage A ----
        if (XF32) {
            const float* X = (const float*)Xv;
            #pragma unroll
            for (int p = 0; p < 8; ++p) {
                const int row = p*16 + (tid >> 4);
                const int fc  = tid & 15;          // 16-B f32 chunk in row
                float4 u = *(const float4*)(X + (size_t)(i0+row)*E_DIM + k0 + fc*4);
                uint2 d;
                d.x = pack2bf(u.x, u.y);
                d.y = pack2bf(u.z, u.w);
                const int slot = (fc >> 1) ^ (row & 7);
                *(uint2*)&As[row*LDK + slot*8 + (fc & 1)*4] = d;
            }
        } else {
            const unsigned short* X = (const unsigned short*)Xv;
            #pragma unroll
            for (int c = 0; c < 4; ++c) {
                const int rbase = c*32 + w*8;
                async16(X + (size_t)(i0 + rbase + srow8)*E_DIM + k0 + schunk*8,
                        &As[rbase*LDK]);
            }
        }
        // ---- stage B (always gload_lds) ----
        #pragma unroll
        for (int c = 0; c < 4; ++c) {
            const int rbase = c*32 + w*8;
            async16(Wt + (size_t)(j0 + rbase + srow8)*E_DIM + k0 + schunk*8,
                    &Bs[rbase*LDK]);
        }
        __syncthreads();
        // ---- compute: 2 halves x (8 ds_read_b128 + 16 MFMA) ----
        #pragma unroll
        for (int half = 0; half < 2; ++half) {
            bf16x8 a[4], b[4];
            #pragma unroll
            for (int m = 0; m < 4; ++m) {
                const int row = wr*64 + m*16 + l15;
                const int slot = (half*4 + lg) ^ (row & 7);
                a[m] = *(const bf16x8*)&As[row*LDK + slot*8];
            }
            #pragma unroll
            for (int n = 0; n < 4; ++n) {
                const int row = wc*64 + n*16 + l15;
                const int slot = (half*4 + lg) ^ (row & 7);
                b[n] = *(const bf16x8*)&Bs[row*LDK + slot*8];
            }
            #pragma unroll
            for (int m = 0; m < 4; ++m)
                #pragma unroll
                for (int n = 0; n < 4; ++n)
                    acc[m][n] = __builtin_amdgcn_mfma_f32_16x16x32_bf16(a[m], b[n], acc[m][n], 0, 0, 0);
        }
        __syncthreads();
    }

    // ---- epilogue. C/D: col=lane&15, row=(lane>>4)*4+reg ----
    float bv[4];
    #pragma unroll
    for (int n = 0; n < 4; ++n) bv[n] = bias[j0 + wc*64 + n*16 + l15];

    #pragma unroll
    for (int m = 0; m < 4; ++m) {
        #pragma unroll
        for (int r = 0; r < 4; ++r) {
            float v0 = acc[m][0][r] + bv[0];
            float v1 = acc[m][1][r] + bv[1];
            float v2 = acc[m][2][r] + bv[2];
            float v3 = acc[m][3][r] + bv[3];
            if (SMAX) {
                // row softmax over this head's 64 cols = {n x l15}
                float mx = fmaxf(fmaxf(v0, v1), fmaxf(v2, v3));
                mx = fmaxf(mx, __shfl_xor(mx, 1));
                mx = fmaxf(mx, __shfl_xor(mx, 2));
                mx = fmaxf(mx, __shfl_xor(mx, 4));
                mx = fmaxf(mx, __shfl_xor(mx, 8));
                v0 = __expf(v0 - mx); v1 = __expf(v1 - mx);
                v2 = __expf(v2 - mx); v3 = __expf(v3 - mx);
                float s = v0 + v1 + v2 + v3;
                s += __shfl_xor(s, 1);
                s += __shfl_xor(s, 2);
                s += __shfl_xor(s, 4);
                s += __shfl_xor(s, 8);
                float inv = 1.f / s;
                v0 *= inv; v1 *= inv; v2 *= inv; v3 *= inv;
            }
            const size_t rowo = (size_t)(i0 + wr*64 + m*16 + lg*4 + r)*E_DIM;
            const int colb = j0 + wc*64 + l15;
            if (OUTF32) {
                float* out = (float*)outv;
                out[rowo + colb     ] = v0;
                out[rowo + colb + 16] = v1;
                out[rowo + colb + 32] = v2;
                out[rowo + colb + 48] = v3;
            } else {
                unsigned short* out = (unsigned short*)outv;
                out[rowo + colb     ] = f2bf(v0);
                out[rowo + colb + 16] = f2bf(v1);
                out[rowo + colb + 32] = f2bf(v2);
                out[rowo + colb + 48] = f2bf(v3);
            }
        }
    }
}

// ---------------------------------------------------------------------------
// K3a/K3b: column sums of exp(k) over S (the k-softmax denominator)
// vectorized: thread handles 4 consecutive e via uint2 loads
// ---------------------------------------------------------------------------
__global__ __launch_bounds__(256)
void k_colsum_part(const unsigned short* __restrict__ K, const unsigned char* __restrict__ mask,
                   float* __restrict__ part)
{
    const int sb = blockIdx.x;                        // 0..15
    const int b  = blockIdx.y;
    const int e4 = threadIdx.x * 4;
    const int s0 = sb * 256;
    const unsigned short* kp = K + ((size_t)b*SEQ + s0)*E_DIM + e4;
    const unsigned char* mp = mask + b*SEQ + s0;
    float a0=0.f, a1=0.f, a2=0.f, a3=0.f;
    for (int s = 0; s < 256; ++s) {
        uint2 u = *(const uint2*)(kp + (size_t)s*E_DIM);
        if (!mp[s]) {
            a0 += __expf(bf2f((unsigned short)(u.x & 0xFFFF)));
            a1 += __expf(bf2f((unsigned short)(u.x >> 16)));
            a2 += __expf(bf2f((unsigned short)(u.y & 0xFFFF)));
            a3 += __expf(bf2f((unsigned short)(u.y >> 16)));
        }
    }
    float* pp = part + ((size_t)b*16 + sb)*E_DIM + e4;
    pp[0]=a0; pp[1]=a1; pp[2]=a2; pp[3]=a3;
}

__global__ __launch_bounds__(256)
void k_colsum_final(const float* __restrict__ part, float* __restrict__ colsum)
{
    int idx = blockIdx.x * 256 + threadIdx.x;  // 4096
    int b = idx >> 10, e = idx & 1023;
    float s = 0.f;
    for (int p = 0; p < 16; ++p) s += part[((size_t)b*16 + p)*E_DIM + e];
    colsum[idx] = s;
}

__global__ __launch_bounds__(256)
void zero_ctx(float* __restrict__ ctx)
{
    ctx[blockIdx.x * 256 + threadIdx.x] = 0.f;
}

// ---------------------------------------------------------------------------
// K4: ctx[b,h,d,e] += sum_{s in chunk} exp(k[b,s,h,d]) * v[b,s,h,e]
// ---------------------------------------------------------------------------
__global__ __launch_bounds__(256)
void context_partial(const unsigned short* __restrict__ K, const unsigned short* __restrict__ V,
                     const unsigned char* __restrict__ mask, float* __restrict__ ctx)
{
    __shared__ float kx[32][65];
    __shared__ float vx[32][65];
    const int h = blockIdx.x, sb = blockIdx.y, b = blockIdx.z;
    const int tid = threadIdx.x;
    const int tx = tid & 15, ty = tid >> 4;
    float acc[4][4] = {};
    const int sbase = sb * 256;
    for (int sc = 0; sc < 256; sc += 32) {
        const int row = tid >> 3;
        const int cb  = (tid & 7) * 8;
        const int s   = sbase + sc + row;
        const size_t gof = ((size_t)b*SEQ + s)*E_DIM + h*DHEAD + cb;
        const bool msk = mask[b*SEQ + s] != 0;
        uint4 ku = *(const uint4*)(K + gof);
        uint4 vu = *(const uint4*)(V + gof);
        const unsigned short* ks = (const unsigned short*)&ku;
        const unsigned short* vs = (const unsigned short*)&vu;
        #pragma unroll
        for (int c = 0; c < 8; ++c) {
            kx[row][cb+c] = msk ? 0.f : __expf(bf2f(ks[c]));
            vx[row][cb+c] = bf2f(vs[c]);
        }
        __syncthreads();
        #pragma unroll
        for (int kk = 0; kk < 32; ++kk) {
            float a[4], bb[4];
            #pragma unroll
            for (int r = 0; r < 4; ++r) a[r] = kx[kk][ty*4+r];
            #pragma unroll
            for (int c = 0; c < 4; ++c) bb[c] = vx[kk][tx*4+c];
            #pragma unroll
            for (int r = 0; r < 4; ++r)
                #pragma unroll
                for (int c = 0; c < 4; ++c)
                    acc[r][c] = fmaf(a[r], bb[c], acc[r][c]);
        }
        __syncthreads();
    }
    #pragma unroll
    for (int r = 0; r < 4; ++r)
        #pragma unroll
        for (int c = 0; c < 4; ++c)
            atomicAdd(&ctx[(((size_t)b*HEADS + h)*DHEAD + ty*4+r)*DHEAD + tx*4+c], acc[r][c]);
}

// ---------------------------------------------------------------------------
// K5: attn[b,s,h,e] = sum_d q_norm[b,s,h,d] * (ctx[b,h,d,e]/colsum[b,h,d])
// ---------------------------------------------------------------------------
__global__ __launch_bounds__(256)
void attn_rows(const unsigned short* __restrict__ QN, const float* __restrict__ ctx,
               const float* __restrict__ colsum, unsigned short* __restrict__ attn)
{
    __shared__ float cs[64][65];
    __shared__ float qs[64][65];
    const int rb = blockIdx.x, h = blockIdx.y, b = blockIdx.z;
    const int tid = threadIdx.x;
    const int tx = tid & 15, ty = tid >> 4;
    for (int t = tid; t < 4096; t += 256) {
        int d = t >> 6, e = t & 63;
        cs[d][e] = ctx[(((size_t)b*HEADS + h)*DHEAD + d)*DHEAD + e]
                 / colsum[b*E_DIM + h*DHEAD + d];
    }
    const int s0 = rb * 64;
    for (int t = tid; t < 4096; t += 256) {
        int i = t >> 6, d = t & 63;
        qs[i][d] = bf2f(QN[((size_t)b*SEQ + s0 + i)*E_DIM + h*DHEAD + d]);
    }
    __syncthreads();
    float acc[4][4] = {};
    for (int kk = 0; kk < 64; ++kk) {
        float a[4], bb[4];
        #pragma unroll
        for (int r = 0; r < 4; ++r) a[r] = qs[ty*4+r][kk];
        #pragma unroll
        for (int c = 0; c < 4; ++c) bb[c] = cs[kk][tx*4+c];
        #pragma unroll
        for (int r = 0; r < 4; ++r)
            #pragma unroll
            for (int c = 0; c < 4; ++c)
                acc[r][c] = fmaf(a[r], bb[c], acc[r][c]);
    }
    #pragma unroll
    for (int r = 0; r < 4; ++r) {
        union { unsigned short h4[4]; uint2 u; } o;
        #pragma unroll
        for (int c = 0; c < 4; ++c) o.h4[c] = f2bf(acc[r][c]);
        *(uint2*)(attn + ((size_t)b*SEQ + s0 + ty*4 + r)*E_DIM + h*DHEAD + tx*4) = o.u;
    }
}

// ---------------------------------------------------------------------------
extern "C" void kernel_launch(void* const* d_in, const int* in_sizes, int n_in,
                              void* d_out, int out_size, void* d_ws, size_t ws_size,
                              hipStream_t stream)
{
    const float* query = (const float*)d_in[0];
    const float* key   = (const float*)d_in[1];
    const float* value = (const float*)d_in[2];
    const unsigned char* mask = (const unsigned char*)d_in[3];
    const float* Wq  = (const float*)d_in[4];
    const float* bq  = (const float*)d_in[5];
    const float* Wk  = (const float*)d_in[6];
    const float* bk  = (const float*)d_in[7];
    const float* Wv  = (const float*)d_in[8];
    const float* bv  = (const float*)d_in[9];
    const float* qla = (const float*)d_in[10];
    const float* qlb = (const float*)d_in[11];
    const float* kla = (const float*)d_in[12];
    const float* klb = (const float*)d_in[13];
    const float* vla = (const float*)d_in[14];
    const float* vlb = (const float*)d_in[15];
    const float* Wo  = (const float*)d_in[16];
    const float* bo  = (const float*)d_in[17];

    const size_t NEEDED = 110379008ULL;
    if (ws_size < NEEDED) {   // report budget (MB) via absmax channel
        ws_sentinel<<<1, 256, 0, stream>>>((float*)d_out, (float)(ws_size >> 20));
        return;
    }

    char* ws = (char*)d_ws;
    unsigned short* Wt     = (unsigned short*)(ws + 0);            // 8 MB
    unsigned short* qn     = (unsigned short*)(ws + 8388608);      // 32 MB
    unsigned short* kbuf   = (unsigned short*)(ws + 41943040);     // 32 MB (reused as attn)
    unsigned short* vbuf   = (unsigned short*)(ws + 75497472);     // 32 MB
    float*          part   = (float*)(ws + 109051904);             // 256 KB
    float*          colsum = (float*)(ws + 109314048);             // 16 KB
    float*          ctx    = (float*)(ws + 109330432);             // 1 MB
    unsigned short* attn   = kbuf;   // kbuf dead after context_partial

    prep_weights_t<<<dim3(32, 32, 4), 256, 0, stream>>>(Wq, Wk, Wv, Wo,
                                                        qla, qlb, kla, klb, vla, vlb, Wt);
    mfma_gemm<1,1,0><<<dim3(128, 8), 256, 0, stream>>>(query, Wt,           bq, qn);
    mfma_gemm<1,0,0><<<dim3(128, 8), 256, 0, stream>>>(key,   Wt + 1048576, bk, kbuf);
    mfma_gemm<1,0,0><<<dim3(128, 8), 256, 0, stream>>>(value, Wt + 2097152, bv, vbuf);
    k_colsum_part<<<dim3(16, BATCH), 256, 0, stream>>>(kbuf, mask, part);
    k_colsum_final<<<16, 256, 0, stream>>>(part, colsum);
    zero_ctx<<<1024, 256, 0, stream>>>(ctx);
    context_partial<<<dim3(HEADS, 16, BATCH), 256, 0, stream>>>(kbuf, vbuf, mask, ctx);
    attn_rows<<<dim3(64, HEADS, BATCH), 256, 0, stream>>>(qn, ctx, colsum, attn);
    mfma_gemm<0,0,1><<<dim3(128, 8), 256, 0, stream>>>(attn, Wt + 3145728, bo, (float*)d_out);
}

// Round 7
// 409.580 us; speedup vs baseline: 1.3991x; 1.3991x over previous
//
#include <hip/hip_runtime.h>
#include <hip/hip_bf16.h>

#define E_DIM 1024
#define HEADS 16
#define DHEAD 64
#define RANK 8
#define BATCH 4
#define SEQ 4096
#define MTOT (BATCH*SEQ)
#define LDK 64   // shorts per LDS row (128 B), BK=64

typedef short bf16x8 __attribute__((ext_vector_type(8)));
typedef float f32x4  __attribute__((ext_vector_type(4)));

__device__ __forceinline__ float bf2f(unsigned short u) {
    return __uint_as_float(((unsigned int)u) << 16);
}
__device__ __forceinline__ unsigned short f2bf(float f) {
    unsigned int x = __float_as_uint(f);
    unsigned int r = (x + 0x7fffu + ((x >> 16) & 1u)) >> 16;
    return (unsigned short)r;
}
// pack two f32 -> two bf16 (round-half-up; bias 2^-17, negligible)
__device__ __forceinline__ unsigned int pack2bf(float lo, float hi) {
    unsigned int l = __float_as_uint(lo), h = __float_as_uint(hi);
    return ((h + 0x8000u) & 0xFFFF0000u) | ((l + 0x8000u) >> 16);
}
// async global->LDS, 16 B per lane, wave-uniform LDS base
__device__ __forceinline__ void async16(const void* g, void* l) {
    __builtin_amdgcn_global_load_lds(
        (const __attribute__((address_space(1))) unsigned int*)g,
        (__attribute__((address_space(3))) unsigned int*)l, 16, 0, 0);
}

// ---------------------------------------------------------------------------
// sentinel: report ws_size (MB) through the absmax channel if budget too small
// ---------------------------------------------------------------------------
__global__ __launch_bounds__(256)
void ws_sentinel(float* __restrict__ out, float mb)
{
    out[threadIdx.x] = mb;
}

// ---------------------------------------------------------------------------
// K1: Wt[g][n][k] = bf16( W[g][k][n] + sum_r A[g][k][r] B[g][r][n] )
// ---------------------------------------------------------------------------
__global__ __launch_bounds__(256)
void prep_weights_t(const float* __restrict__ Wq, const float* __restrict__ Wk,
                    const float* __restrict__ Wv, const float* __restrict__ Wo,
                    const float* __restrict__ qa, const float* __restrict__ qb,
                    const float* __restrict__ ka, const float* __restrict__ kb,
                    const float* __restrict__ va, const float* __restrict__ vb,
                    unsigned short* __restrict__ Wt)
{
    __shared__ float tile[32][33];
    const int n0 = blockIdx.x * 32;
    const int k0 = blockIdx.y * 32;
    const int g  = blockIdx.z;
    const float* W = (g==0)?Wq:(g==1)?Wk:(g==2)?Wv:Wo;
    const float* A = (g==0)?qa:(g==1)?ka:va;
    const float* Bm= (g==0)?qb:(g==1)?kb:vb;
    const int t  = threadIdx.x;
    const int r  = t >> 3;
    const int c4 = (t & 7) * 4;

    float4 v = *(const float4*)(W + (size_t)(k0 + r)*E_DIM + n0 + c4);
    float o0=v.x, o1=v.y, o2=v.z, o3=v.w;
    if (g < 3) {
        #pragma unroll
        for (int rr = 0; rr < RANK; ++rr) {
            float av = A[(k0 + r)*RANK + rr];
            const float* bp = Bm + (size_t)rr*E_DIM + n0 + c4;
            o0 = fmaf(av, bp[0], o0);
            o1 = fmaf(av, bp[1], o1);
            o2 = fmaf(av, bp[2], o2);
            o3 = fmaf(av, bp[3], o3);
        }
    }
    tile[r][c4+0]=o0; tile[r][c4+1]=o1; tile[r][c4+2]=o2; tile[r][c4+3]=o3;
    __syncthreads();
    union { unsigned short h[4]; uint2 u; } o;
    #pragma unroll
    for (int i = 0; i < 4; ++i) o.h[i] = f2bf(tile[c4+i][r]);
    *(uint2*)(Wt + (size_t)g*1048576 + (size_t)(n0 + r)*E_DIM + k0 + c4) = o.u;
}

// ---------------------------------------------------------------------------
// K2: MFMA GEMM  C[M,1024] = X[M,1024] @ Wt[1024n,1024k]^T + bias
// 128x128 tile, BK=64, 4 waves (2x2 of 64x64), 16x16x32 bf16 MFMA.
// LDS linear [128][64] bf16, chunk XOR-swizzle (slot = chunk ^ (row&7)).
// MODE 0: plain.  MODE 1: fused per-head q-softmax (64-col wave span).
// MODE 2: fused masked exp-colsum atomics into colsum[b*1024+col] (k proj).
// ---------------------------------------------------------------------------
template<int XF32, int MODE, int OUTF32>
__global__ __launch_bounds__(256)
void mfma_gemm(const void* __restrict__ Xv, const unsigned short* __restrict__ Wt,
               const float* __restrict__ bias, void* __restrict__ outv,
               const unsigned char* __restrict__ maskp, float* __restrict__ colsum)
{
    __shared__ __align__(16) unsigned short As[128*LDK];
    __shared__ __align__(16) unsigned short Bs[128*LDK];
    const int tid  = threadIdx.x;
    const int lane = tid & 63;
    const int w    = tid >> 6;
    const int wr   = w >> 1, wc = w & 1;
    const int i0   = blockIdx.x * 128;   // i-panel major: same-XCD j-sharing
    const int j0   = blockIdx.y * 128;
    const int l15  = lane & 15, lg = lane >> 4;

    const int srow8  = lane >> 3;                  // row within 8-row group
    const int schunk = (lane & 7) ^ srow8;         // pre-swizzled source chunk

    f32x4 acc[4][4];
    #pragma unroll
    for (int m = 0; m < 4; ++m)
        #pragma unroll
        for (int n = 0; n < 4; ++n) {
            f32x4 z = {0.f, 0.f, 0.f, 0.f};
            acc[m][n] = z;
        }

    for (int k0 = 0; k0 < E_DIM; k0 += 64) {
        // ---- stage A ----
        if (XF32) {
            const float* X = (const float*)Xv;
            #pragma unroll
            for (int p = 0; p < 8; ++p) {
                const int row = p*16 + (tid >> 4);
                const int fc  = tid & 15;          // 16-B f32 chunk in row
                float4 u = *(const float4*)(X + (size_t)(i0+row)*E_DIM + k0 + fc*4);
                uint2 d;
                d.x = pack2bf(u.x, u.y);
                d.y = pack2bf(u.z, u.w);
                const int slot = (fc >> 1) ^ (row & 7);
                *(uint2*)&As[row*LDK + slot*8 + (fc & 1)*4] = d;
            }
        } else {
            const unsigned short* X = (const unsigned short*)Xv;
            #pragma unroll
            for (int c = 0; c < 4; ++c) {
                const int rbase = c*32 + w*8;
                async16(X + (size_t)(i0 + rbase + srow8)*E_DIM + k0 + schunk*8,
                        &As[rbase*LDK]);
            }
        }
        // ---- stage B (always gload_lds) ----
        #pragma unroll
        for (int c = 0; c < 4; ++c) {
            const int rbase = c*32 + w*8;
            async16(Wt + (size_t)(j0 + rbase + srow8)*E_DIM + k0 + schunk*8,
                    &Bs[rbase*LDK]);
        }
        __syncthreads();
        // ---- compute: 2 halves x (8 ds_read_b128 + 16 MFMA) ----
        #pragma unroll
        for (int half = 0; half < 2; ++half) {
            bf16x8 a[4], b[4];
            #pragma unroll
            for (int m = 0; m < 4; ++m) {
                const int row = wr*64 + m*16 + l15;
                const int slot = (half*4 + lg) ^ (row & 7);
                a[m] = *(const bf16x8*)&As[row*LDK + slot*8];
            }
            #pragma unroll
            for (int n = 0; n < 4; ++n) {
                const int row = wc*64 + n*16 + l15;
                const int slot = (half*4 + lg) ^ (row & 7);
                b[n] = *(const bf16x8*)&Bs[row*LDK + slot*8];
            }
            #pragma unroll
            for (int m = 0; m < 4; ++m)
                #pragma unroll
                for (int n = 0; n < 4; ++n)
                    acc[m][n] = __builtin_amdgcn_mfma_f32_16x16x32_bf16(a[m], b[n], acc[m][n], 0, 0, 0);
        }
        __syncthreads();
    }

    // ---- epilogue. C/D: col=lane&15, row=(lane>>4)*4+reg ----
    float bv[4];
    #pragma unroll
    for (int n = 0; n < 4; ++n) bv[n] = bias[j0 + wc*64 + n*16 + l15];

    float psum[4] = {0.f, 0.f, 0.f, 0.f};   // MODE 2 column partials

    #pragma unroll
    for (int m = 0; m < 4; ++m) {
        #pragma unroll
        for (int r = 0; r < 4; ++r) {
            float v0 = acc[m][0][r] + bv[0];
            float v1 = acc[m][1][r] + bv[1];
            float v2 = acc[m][2][r] + bv[2];
            float v3 = acc[m][3][r] + bv[3];
            if (MODE == 1) {
                // row softmax over this head's 64 cols = {n x l15}
                float mx = fmaxf(fmaxf(v0, v1), fmaxf(v2, v3));
                mx = fmaxf(mx, __shfl_xor(mx, 1));
                mx = fmaxf(mx, __shfl_xor(mx, 2));
                mx = fmaxf(mx, __shfl_xor(mx, 4));
                mx = fmaxf(mx, __shfl_xor(mx, 8));
                v0 = __expf(v0 - mx); v1 = __expf(v1 - mx);
                v2 = __expf(v2 - mx); v3 = __expf(v3 - mx);
                float s = v0 + v1 + v2 + v3;
                s += __shfl_xor(s, 1);
                s += __shfl_xor(s, 2);
                s += __shfl_xor(s, 4);
                s += __shfl_xor(s, 8);
                float inv = 1.f / s;
                v0 *= inv; v1 *= inv; v2 *= inv; v3 *= inv;
            }
            const int grow = i0 + wr*64 + m*16 + lg*4 + r;
            if (MODE == 2) {
                if (!maskp[grow]) {
                    psum[0] += __expf(v0);
                    psum[1] += __expf(v1);
                    psum[2] += __expf(v2);
                    psum[3] += __expf(v3);
                }
            }
            const size_t rowo = (size_t)grow * E_DIM;
            const int colb = j0 + wc*64 + l15;
            if (OUTF32) {
                float* out = (float*)outv;
                out[rowo + colb     ] = v0;
                out[rowo + colb + 16] = v1;
                out[rowo + colb + 32] = v2;
                out[rowo + colb + 48] = v3;
            } else {
                unsigned short* out = (unsigned short*)outv;
                out[rowo + colb     ] = f2bf(v0);
                out[rowo + colb + 16] = f2bf(v1);
                out[rowo + colb + 32] = f2bf(v2);
                out[rowo + colb + 48] = f2bf(v3);
            }
        }
    }
    if (MODE == 2) {
        const int b = i0 >> 12;   // 4096 rows per batch
        #pragma unroll
        for (int n = 0; n < 4; ++n) {
            float s = psum[n];
            s += __shfl_xor(s, 16);
            s += __shfl_xor(s, 32);
            if (lg == 0)
                atomicAdd(&colsum[b*E_DIM + j0 + wc*64 + n*16 + l15], s);
        }
    }
}

// ---------------------------------------------------------------------------
// zero colsum (16 KB) + ctx (1 MB), contiguous: 266240 floats
// ---------------------------------------------------------------------------
__global__ __launch_bounds__(256)
void zero_acc(float* __restrict__ p)
{
    p[blockIdx.x * 256 + threadIdx.x] = 0.f;
}

// ---------------------------------------------------------------------------
// K4: ctx[b,h,d,e] += sum_{s in chunk} exp(k[b,s,h,d]) * v[b,s,h,e]
// ---------------------------------------------------------------------------
__global__ __launch_bounds__(256)
void context_partial(const unsigned short* __restrict__ K, const unsigned short* __restrict__ V,
                     const unsigned char* __restrict__ mask, float* __restrict__ ctx)
{
    __shared__ float kx[32][65];
    __shared__ float vx[32][65];
    const int h = blockIdx.x, sb = blockIdx.y, b = blockIdx.z;
    const int tid = threadIdx.x;
    const int tx = tid & 15, ty = tid >> 4;
    float acc[4][4] = {};
    const int sbase = sb * 256;
    for (int sc = 0; sc < 256; sc += 32) {
        const int row = tid >> 3;
        const int cb  = (tid & 7) * 8;
        const int s   = sbase + sc + row;
        const size_t gof = ((size_t)b*SEQ + s)*E_DIM + h*DHEAD + cb;
        const bool msk = mask[b*SEQ + s] != 0;
        uint4 ku = *(const uint4*)(K + gof);
        uint4 vu = *(const uint4*)(V + gof);
        const unsigned short* ks = (const unsigned short*)&ku;
        const unsigned short* vs = (const unsigned short*)&vu;
        #pragma unroll
        for (int c = 0; c < 8; ++c) {
            kx[row][cb+c] = msk ? 0.f : __expf(bf2f(ks[c]));
            vx[row][cb+c] = bf2f(vs[c]);
        }
        __syncthreads();
        #pragma unroll
        for (int kk = 0; kk < 32; ++kk) {
            float a[4], bb[4];
            #pragma unroll
            for (int r = 0; r < 4; ++r) a[r] = kx[kk][ty*4+r];
            #pragma unroll
            for (int c = 0; c < 4; ++c) bb[c] = vx[kk][tx*4+c];
            #pragma unroll
            for (int r = 0; r < 4; ++r)
                #pragma unroll
                for (int c = 0; c < 4; ++c)
                    acc[r][c] = fmaf(a[r], bb[c], acc[r][c]);
        }
        __syncthreads();
    }
    #pragma unroll
    for (int r = 0; r < 4; ++r)
        #pragma unroll
        for (int c = 0; c < 4; ++c)
            atomicAdd(&ctx[(((size_t)b*HEADS + h)*DHEAD + ty*4+r)*DHEAD + tx*4+c], acc[r][c]);
}

// ---------------------------------------------------------------------------
// K5: attn[b,s,h,e] = sum_d q_norm[b,s,h,d] * (ctx[b,h,d,e]/colsum[b,h,d])
// ---------------------------------------------------------------------------
__global__ __launch_bounds__(256)
void attn_rows(const unsigned short* __restrict__ QN, const float* __restrict__ ctx,
               const float* __restrict__ colsum, unsigned short* __restrict__ attn)
{
    __shared__ float cs[64][65];
    __shared__ float qs[64][65];
    const int rb = blockIdx.x, h = blockIdx.y, b = blockIdx.z;
    const int tid = threadIdx.x;
    const int tx = tid & 15, ty = tid >> 4;
    for (int t = tid; t < 4096; t += 256) {
        int d = t >> 6, e = t & 63;
        cs[d][e] = ctx[(((size_t)b*HEADS + h)*DHEAD + d)*DHEAD + e]
                 / colsum[b*E_DIM + h*DHEAD + d];
    }
    const int s0 = rb * 64;
    for (int t = tid; t < 4096; t += 256) {
        int i = t >> 6, d = t & 63;
        qs[i][d] = bf2f(QN[((size_t)b*SEQ + s0 + i)*E_DIM + h*DHEAD + d]);
    }
    __syncthreads();
    float acc[4][4] = {};
    for (int kk = 0; kk < 64; ++kk) {
        float a[4], bb[4];
        #pragma unroll
        for (int r = 0; r < 4; ++r) a[r] = qs[ty*4+r][kk];
        #pragma unroll
        for (int c = 0; c < 4; ++c) bb[c] = cs[kk][tx*4+c];
        #pragma unroll
        for (int r = 0; r < 4; ++r)
            #pragma unroll
            for (int c = 0; c < 4; ++c)
                acc[r][c] = fmaf(a[r], bb[c], acc[r][c]);
    }
    #pragma unroll
    for (int r = 0; r < 4; ++r) {
        union { unsigned short h4[4]; uint2 u; } o;
        #pragma unroll
        for (int c = 0; c < 4; ++c) o.h4[c] = f2bf(acc[r][c]);
        *(uint2*)(attn + ((size_t)b*SEQ + s0 + ty*4 + r)*E_DIM + h*DHEAD + tx*4) = o.u;
    }
}

// ---------------------------------------------------------------------------
extern "C" void kernel_launch(void* const* d_in, const int* in_sizes, int n_in,
                              void* d_out, int out_size, void* d_ws, size_t ws_size,
                              hipStream_t stream)
{
    const float* query = (const float*)d_in[0];
    const float* key   = (const float*)d_in[1];
    const float* value = (const float*)d_in[2];
    const unsigned char* mask = (const unsigned char*)d_in[3];
    const float* Wq  = (const float*)d_in[4];
    const float* bq  = (const float*)d_in[5];
    const float* Wk  = (const float*)d_in[6];
    const float* bk  = (const float*)d_in[7];
    const float* Wv  = (const float*)d_in[8];
    const float* bv  = (const float*)d_in[9];
    const float* qla = (const float*)d_in[10];
    const float* qlb = (const float*)d_in[11];
    const float* kla = (const float*)d_in[12];
    const float* klb = (const float*)d_in[13];
    const float* vla = (const float*)d_in[14];
    const float* vlb = (const float*)d_in[15];
    const float* Wo  = (const float*)d_in[16];
    const float* bo  = (const float*)d_in[17];

    const size_t NEEDED = 110116864ULL;
    if (ws_size < NEEDED) {   // report budget (MB) via absmax channel
        ws_sentinel<<<1, 256, 0, stream>>>((float*)d_out, (float)(ws_size >> 20));
        return;
    }

    char* ws = (char*)d_ws;
    unsigned short* Wt     = (unsigned short*)(ws + 0);            // 8 MB
    unsigned short* qn     = (unsigned short*)(ws + 8388608);      // 32 MB
    unsigned short* kbuf   = (unsigned short*)(ws + 41943040);     // 32 MB (reused as attn)
    unsigned short* vbuf   = (unsigned short*)(ws + 75497472);     // 32 MB
    float*          colsum = (float*)(ws + 109051904);             // 16 KB
    float*          ctx    = (float*)(ws + 109068288);             // 1 MB
    unsigned short* attn   = kbuf;   // kbuf dead after context_partial

    // zero colsum + ctx (contiguous, 266240 floats)
    zero_acc<<<1040, 256, 0, stream>>>(colsum);
    prep_weights_t<<<dim3(32, 32, 4), 256, 0, stream>>>(Wq, Wk, Wv, Wo,
                                                        qla, qlb, kla, klb, vla, vlb, Wt);
    mfma_gemm<1,1,0><<<dim3(128, 8), 256, 0, stream>>>(query, Wt,           bq, qn,   nullptr, nullptr);
    mfma_gemm<1,2,0><<<dim3(128, 8), 256, 0, stream>>>(key,   Wt + 1048576, bk, kbuf, mask,    colsum);
    mfma_gemm<1,0,0><<<dim3(128, 8), 256, 0, stream>>>(value, Wt + 2097152, bv, vbuf, nullptr, nullptr);
    context_partial<<<dim3(HEADS, 16, BATCH), 256, 0, stream>>>(kbuf, vbuf, mask, ctx);
    attn_rows<<<dim3(64, HEADS, BATCH), 256, 0, stream>>>(qn, ctx, colsum, attn);
    mfma_gemm<0,0,1><<<dim3(128, 8), 256, 0, stream>>>(attn, Wt + 3145728, bo, (float*)d_out, nullptr, nullptr);
}

// Round 8
// 337.497 us; speedup vs baseline: 1.6980x; 1.2136x over previous
//
#include <hip/hip_runtime.h>
#include <hip/hip_bf16.h>

#define E_DIM 1024
#define HEADS 16
#define DHEAD 64
#define RANK 8
#define BATCH 4
#define SEQ 4096
#define MTOT (BATCH*SEQ)
#define LDK 64   // shorts per LDS row (128 B), BK=64

typedef short bf16x8 __attribute__((ext_vector_type(8)));
typedef float f32x4  __attribute__((ext_vector_type(4)));

__device__ __forceinline__ float bf2f(unsigned short u) {
    return __uint_as_float(((unsigned int)u) << 16);
}
__device__ __forceinline__ unsigned short f2bf(float f) {
    unsigned int x = __float_as_uint(f);
    unsigned int r = (x + 0x7fffu + ((x >> 16) & 1u)) >> 16;
    return (unsigned short)r;
}
__device__ __forceinline__ unsigned int pack2bf(float lo, float hi) {
    unsigned int l = __float_as_uint(lo), h = __float_as_uint(hi);
    return ((h + 0x8000u) & 0xFFFF0000u) | ((l + 0x8000u) >> 16);
}
__device__ __forceinline__ void async16(const void* g, void* l) {
    __builtin_amdgcn_global_load_lds(
        (const __attribute__((address_space(1))) unsigned int*)g,
        (__attribute__((address_space(3))) unsigned int*)l, 16, 0, 0);
}

// ---------------------------------------------------------------------------
__global__ __launch_bounds__(256)
void ws_sentinel(float* __restrict__ out, float mb)
{
    out[threadIdx.x] = mb;
}

__global__ __launch_bounds__(256)
void zero_colsum(float* __restrict__ p)
{
    p[blockIdx.x * 256 + threadIdx.x] = 0.f;
}

// ---------------------------------------------------------------------------
// K1: Wt[g][n][k] = bf16( W[g][k][n] + sum_r A[g][k][r] B[g][r][n] )
// ---------------------------------------------------------------------------
__global__ __launch_bounds__(256)
void prep_weights_t(const float* __restrict__ Wq, const float* __restrict__ Wk,
                    const float* __restrict__ Wv, const float* __restrict__ Wo,
                    const float* __restrict__ qa, const float* __restrict__ qb,
                    const float* __restrict__ ka, const float* __restrict__ kb,
                    const float* __restrict__ va, const float* __restrict__ vb,
                    unsigned short* __restrict__ Wt)
{
    __shared__ float tile[32][33];
    const int n0 = blockIdx.x * 32;
    const int k0 = blockIdx.y * 32;
    const int g  = blockIdx.z;
    const float* W = (g==0)?Wq:(g==1)?Wk:(g==2)?Wv:Wo;
    const float* A = (g==0)?qa:(g==1)?ka:va;
    const float* Bm= (g==0)?qb:(g==1)?kb:vb;
    const int t  = threadIdx.x;
    const int r  = t >> 3;
    const int c4 = (t & 7) * 4;

    float4 v = *(const float4*)(W + (size_t)(k0 + r)*E_DIM + n0 + c4);
    float o0=v.x, o1=v.y, o2=v.z, o3=v.w;
    if (g < 3) {
        #pragma unroll
        for (int rr = 0; rr < RANK; ++rr) {
            float av = A[(k0 + r)*RANK + rr];
            const float* bp = Bm + (size_t)rr*E_DIM + n0 + c4;
            o0 = fmaf(av, bp[0], o0);
            o1 = fmaf(av, bp[1], o1);
            o2 = fmaf(av, bp[2], o2);
            o3 = fmaf(av, bp[3], o3);
        }
    }
    tile[r][c4+0]=o0; tile[r][c4+1]=o1; tile[r][c4+2]=o2; tile[r][c4+3]=o3;
    __syncthreads();
    union { unsigned short h[4]; uint2 u; } o;
    #pragma unroll
    for (int i = 0; i < 4; ++i) o.h[i] = f2bf(tile[c4+i][r]);
    *(uint2*)(Wt + (size_t)g*1048576 + (size_t)(n0 + r)*E_DIM + k0 + c4) = o.u;
}

// ---------------------------------------------------------------------------
// K2: MFMA GEMM  C[M,1024] = X @ Wt^T + bias.  128x128 tile, BK=64, 4 waves.
// MODE 0: plain write.            MODE 1: fused q-softmax write.
// MODE 2: K: transposed write to T[b][dglob][s] + masked exp-colsum atomics.
// MODE 3: V: transposed write only.
// MODE 4: plain write, B operand batched: Wt += (i0>>12)*1M (final proj).
// ---------------------------------------------------------------------------
template<int XF32, int MODE, int OUTF32>
__global__ __launch_bounds__(256)
void mfma_gemm(const void* __restrict__ Xv, const unsigned short* __restrict__ Wt,
               const float* __restrict__ bias, void* __restrict__ outv,
               const unsigned char* __restrict__ maskp, float* __restrict__ colsum)
{
    __shared__ __align__(16) unsigned short SH[16384];   // As | Bs, reused by T-epilogue
    unsigned short* const As = SH;
    unsigned short* const Bs = SH + 8192;
    const int tid  = threadIdx.x;
    const int lane = tid & 63;
    const int w    = tid >> 6;
    const int wr   = w >> 1, wc = w & 1;
    const int i0   = blockIdx.x * 128;   // i-panel major: same-XCD j-sharing
    const int j0   = blockIdx.y * 128;
    const int l15  = lane & 15, lg = lane >> 4;

    const unsigned short* Wb = (MODE == 4) ? Wt + (((size_t)(i0 >> 12)) << 20) : Wt;

    const int srow8  = lane >> 3;
    const int schunk = (lane & 7) ^ srow8;

    f32x4 acc[4][4];
    #pragma unroll
    for (int m = 0; m < 4; ++m)
        #pragma unroll
        for (int n = 0; n < 4; ++n) {
            f32x4 z = {0.f, 0.f, 0.f, 0.f};
            acc[m][n] = z;
        }

    for (int k0 = 0; k0 < E_DIM; k0 += 64) {
        if (XF32) {
            const float* X = (const float*)Xv;
            #pragma unroll
            for (int p = 0; p < 8; ++p) {
                const int row = p*16 + (tid >> 4);
                const int fc  = tid & 15;
                float4 u = *(const float4*)(X + (size_t)(i0+row)*E_DIM + k0 + fc*4);
                uint2 d;
                d.x = pack2bf(u.x, u.y);
                d.y = pack2bf(u.z, u.w);
                const int slot = (fc >> 1) ^ (row & 7);
                *(uint2*)&As[row*LDK + slot*8 + (fc & 1)*4] = d;
            }
        } else {
            const unsigned short* X = (const unsigned short*)Xv;
            #pragma unroll
            for (int c = 0; c < 4; ++c) {
                const int rbase = c*32 + w*8;
                async16(X + (size_t)(i0 + rbase + srow8)*E_DIM + k0 + schunk*8,
                        &As[rbase*LDK]);
            }
        }
        #pragma unroll
        for (int c = 0; c < 4; ++c) {
            const int rbase = c*32 + w*8;
            async16(Wb + (size_t)(j0 + rbase + srow8)*E_DIM + k0 + schunk*8,
                    &Bs[rbase*LDK]);
        }
        __syncthreads();
        #pragma unroll
        for (int half = 0; half < 2; ++half) {
            bf16x8 a[4], b[4];
            #pragma unroll
            for (int m = 0; m < 4; ++m) {
                const int row = wr*64 + m*16 + l15;
                const int slot = (half*4 + lg) ^ (row & 7);
                a[m] = *(const bf16x8*)&As[row*LDK + slot*8];
            }
            #pragma unroll
            for (int n = 0; n < 4; ++n) {
                const int row = wc*64 + n*16 + l15;
                const int slot = (half*4 + lg) ^ (row & 7);
                b[n] = *(const bf16x8*)&Bs[row*LDK + slot*8];
            }
            #pragma unroll
            for (int m = 0; m < 4; ++m)
                #pragma unroll
                for (int n = 0; n < 4; ++n)
                    acc[m][n] = __builtin_amdgcn_mfma_f32_16x16x32_bf16(a[m], b[n], acc[m][n], 0, 0, 0);
        }
        __syncthreads();
    }

    float bv[4];
    #pragma unroll
    for (int n = 0; n < 4; ++n) bv[n] = bias[j0 + wc*64 + n*16 + l15];

    if (MODE == 2 || MODE == 3) {
        // ---- transposed epilogue: SH[jj 0..127][ss 0..127] bf16, slot^ (jj&15)
        float psum[4] = {0.f, 0.f, 0.f, 0.f};
        #pragma unroll
        for (int m = 0; m < 4; ++m) {
            #pragma unroll
            for (int r = 0; r < 4; ++r) {
                const int ss = wr*64 + m*16 + lg*4 + r;
                const bool mk = (MODE == 2) ? (maskp[i0 + ss] != 0) : false;
                #pragma unroll
                for (int n = 0; n < 4; ++n) {
                    float v = acc[m][n][r] + bv[n];
                    if (MODE == 2) { if (!mk) psum[n] += __expf(v); }
                    const int jj = wc*64 + n*16 + l15;
                    SH[jj*128 + (((ss >> 3) ^ (jj & 15)))*8 + (ss & 7)] = f2bf(v);
                }
            }
        }
        if (MODE == 2) {
            const int b = i0 >> 12;
            #pragma unroll
            for (int n = 0; n < 4; ++n) {
                float s = psum[n];
                s += __shfl_xor(s, 16);
                s += __shfl_xor(s, 32);
                if (lg == 0)
                    atomicAdd(&colsum[b*E_DIM + j0 + wc*64 + n*16 + l15], s);
            }
        }
        __syncthreads();
        const int b = i0 >> 12, srel = i0 & 4095;
        unsigned short* T = (unsigned short*)outv;
        const int jj = tid >> 1, hf = tid & 1;
        const size_t gbase = ((size_t)(b*1024 + j0 + jj))*4096 + srel + hf*64;
        #pragma unroll
        for (int c = 0; c < 8; ++c) {
            const int slot = hf*8 + c;
            uint4 u = *(const uint4*)&SH[jj*128 + ((slot ^ (jj & 15)))*8];
            *(uint4*)(T + gbase + c*8) = u;
        }
        return;
    }

    #pragma unroll
    for (int m = 0; m < 4; ++m) {
        #pragma unroll
        for (int r = 0; r < 4; ++r) {
            float v0 = acc[m][0][r] + bv[0];
            float v1 = acc[m][1][r] + bv[1];
            float v2 = acc[m][2][r] + bv[2];
            float v3 = acc[m][3][r] + bv[3];
            if (MODE == 1) {
                float mx = fmaxf(fmaxf(v0, v1), fmaxf(v2, v3));
                mx = fmaxf(mx, __shfl_xor(mx, 1));
                mx = fmaxf(mx, __shfl_xor(mx, 2));
                mx = fmaxf(mx, __shfl_xor(mx, 4));
                mx = fmaxf(mx, __shfl_xor(mx, 8));
                v0 = __expf(v0 - mx); v1 = __expf(v1 - mx);
                v2 = __expf(v2 - mx); v3 = __expf(v3 - mx);
                float s = v0 + v1 + v2 + v3;
                s += __shfl_xor(s, 1);
                s += __shfl_xor(s, 2);
                s += __shfl_xor(s, 4);
                s += __shfl_xor(s, 8);
                float inv = 1.f / s;
                v0 *= inv; v1 *= inv; v2 *= inv; v3 *= inv;
            }
            const size_t rowo = (size_t)(i0 + wr*64 + m*16 + lg*4 + r) * E_DIM;
            const int colb = j0 + wc*64 + l15;
            if (OUTF32) {
                float* out = (float*)outv;
                out[rowo + colb     ] = v0;
                out[rowo + colb + 16] = v1;
                out[rowo + colb + 32] = v2;
                out[rowo + colb + 48] = v3;
            } else {
                unsigned short* out = (unsigned short*)outv;
                out[rowo + colb     ] = f2bf(v0);
                out[rowo + colb + 16] = f2bf(v1);
                out[rowo + colb + 32] = f2bf(v2);
                out[rowo + colb + 48] = f2bf(v3);
            }
        }
    }
}

// ---------------------------------------------------------------------------
// K4: context via MFMA.  partial[sb][b][h][d][e] = sum_{s in 256-chunk}
//     expk[s][d]*v[s][e], from K_T/V_T [b][dglob][4096 s] (k-contiguous).
// Per block: (sb,h,b), 2 sub-tiles of 128 s. LDS [64][128] bf16, 16-slot XOR.
// 4 waves: 32x32 quadrants. No atomics.
// ---------------------------------------------------------------------------
__global__ __launch_bounds__(256)
void context_mfma(const unsigned short* __restrict__ KT,
                  const unsigned short* __restrict__ VT,
                  const unsigned char* __restrict__ mask,
                  float* __restrict__ partial)
{
    __shared__ __align__(16) unsigned short Ks[64*128];
    __shared__ __align__(16) unsigned short Vs[64*128];
    const int sb = blockIdx.x, h = blockIdx.y, b = blockIdx.z;
    const int tid = threadIdx.x, lane = tid & 63, w = tid >> 6;
    const int wr = w >> 1, wc = w & 1;
    const int l15 = lane & 15, lg = lane >> 4;
    const int srow = tid >> 2;          // 0..63
    const int sq0  = (tid & 3) * 4;     // 4 slots of 8 s

    f32x4 acc[2][2];
    #pragma unroll
    for (int m = 0; m < 2; ++m)
        #pragma unroll
        for (int n = 0; n < 2; ++n) {
            f32x4 z = {0.f, 0.f, 0.f, 0.f};
            acc[m][n] = z;
        }

    for (int st = 0; st < 2; ++st) {
        const int s0 = sb*256 + st*128;
        const unsigned short* kt = KT + ((size_t)(b*1024 + h*64 + srow))*4096 + s0;
        const unsigned short* vt = VT + ((size_t)(b*1024 + h*64 + srow))*4096 + s0;
        const unsigned char*  mp = mask + b*SEQ + s0;
        #pragma unroll
        for (int qi = 0; qi < 4; ++qi) {
            const int slot = sq0 + qi;
            uint4 u = *(const uint4*)(kt + slot*8);
            uint2 mk = *(const uint2*)(mp + slot*8);
            const unsigned char* mb = (const unsigned char*)&mk;
            const unsigned short* us = (const unsigned short*)&u;
            float e[8];
            #pragma unroll
            for (int i = 0; i < 8; ++i)
                e[i] = mb[i] ? 0.f : __expf(bf2f(us[i]));
            uint4 p;
            p.x = pack2bf(e[0], e[1]);
            p.y = pack2bf(e[2], e[3]);
            p.z = pack2bf(e[4], e[5]);
            p.w = pack2bf(e[6], e[7]);
            *(uint4*)&Ks[srow*128 + ((slot ^ (srow & 15)))*8] = p;
            uint4 uv = *(const uint4*)(vt + slot*8);
            *(uint4*)&Vs[srow*128 + ((slot ^ (srow & 15)))*8] = uv;
        }
        __syncthreads();
        #pragma unroll
        for (int ks = 0; ks < 4; ++ks) {
            bf16x8 a[2], bq[2];
            #pragma unroll
            for (int mt = 0; mt < 2; ++mt) {
                const int d = wr*32 + mt*16 + l15;
                a[mt] = *(const bf16x8*)&Ks[d*128 + (((ks*4+lg) ^ (d & 15)))*8];
            }
            #pragma unroll
            for (int nt = 0; nt < 2; ++nt) {
                const int e = wc*32 + nt*16 + l15;
                bq[nt] = *(const bf16x8*)&Vs[e*128 + (((ks*4+lg) ^ (e & 15)))*8];
            }
            #pragma unroll
            for (int mt = 0; mt < 2; ++mt)
                #pragma unroll
                for (int nt = 0; nt < 2; ++nt)
                    acc[mt][nt] = __builtin_amdgcn_mfma_f32_16x16x32_bf16(a[mt], bq[nt], acc[mt][nt], 0, 0, 0);
        }
        __syncthreads();
    }
    float* pp = partial + (size_t)sb*(BATCH*HEADS*4096) + ((size_t)(b*HEADS + h))*4096;
    #pragma unroll
    for (int mt = 0; mt < 2; ++mt)
        #pragma unroll
        for (int nt = 0; nt < 2; ++nt)
            #pragma unroll
            for (int r = 0; r < 4; ++r) {
                const int d = wr*32 + mt*16 + lg*4 + r;
                const int e = wc*32 + nt*16 + l15;
                pp[d*64 + e] = acc[mt][nt][r];
            }
}

// ---------------------------------------------------------------------------
// reduce: ctx[i] = sum over 16 partial planes
// ---------------------------------------------------------------------------
__global__ __launch_bounds__(256)
void reduce_ctx(const float* __restrict__ partial, float* __restrict__ ctx)
{
    const int i = blockIdx.x * 256 + threadIdx.x;   // 65536 float4 elems
    const float4* p = (const float4*)partial;
    float4 s = p[i];
    #pragma unroll
    for (int q = 1; q < 16; ++q) {
        float4 u = p[(size_t)q*65536 + i];
        s.x += u.x; s.y += u.y; s.z += u.z; s.w += u.w;
    }
    ((float4*)ctx)[i] = s;
}

// ---------------------------------------------------------------------------
// K5: G_t[b][j][h*64+d] = sum_e WtO[j][h*64+e] * (ctx[b,h,d,e]/colsum[b,h,d])
// grid (jt=8, h=16, b=4). M=j(128), N=d(64), K=e(64). bf16 out.
// ---------------------------------------------------------------------------
__global__ __launch_bounds__(256)
void g_kernel(const unsigned short* __restrict__ WtO, const float* __restrict__ ctx,
              const float* __restrict__ colsum, unsigned short* __restrict__ Gt)
{
    __shared__ __align__(16) unsigned short Aw[128*64];
    __shared__ __align__(16) unsigned short Bc[64*64];
    const int jt = blockIdx.x, h = blockIdx.y, b = blockIdx.z;
    const int tid = threadIdx.x, lane = tid & 63, w = tid >> 6;
    const int l15 = lane & 15, lg = lane >> 4;
    const int j0 = jt * 128;

    {   // stage A: WtO rows j0..+128, cols h*64..+64
        const int ar = tid >> 1, aq0 = (tid & 1) * 4;
        #pragma unroll
        for (int qi = 0; qi < 4; ++qi) {
            const int slot = aq0 + qi;
            uint4 u = *(const uint4*)(WtO + (size_t)(j0 + ar)*E_DIM + h*64 + slot*8);
            *(uint4*)&Aw[ar*64 + ((slot ^ (ar & 7)))*8] = u;
        }
    }
    {   // stage B: cshat[d][e] bf16
        const int br = tid >> 2, bq0 = (tid & 3) * 2;
        const float inv = 1.f / colsum[b*E_DIM + h*64 + br];
        #pragma unroll
        for (int qi = 0; qi < 2; ++qi) {
            const int slot = bq0 + qi;
            const float* cp = ctx + (((size_t)(b*HEADS + h))*64 + br)*64 + slot*8;
            float4 c0 = *(const float4*)cp;
            float4 c1 = *(const float4*)(cp + 4);
            uint4 p;
            p.x = pack2bf(c0.x*inv, c0.y*inv);
            p.y = pack2bf(c0.z*inv, c0.w*inv);
            p.z = pack2bf(c1.x*inv, c1.y*inv);
            p.w = pack2bf(c1.z*inv, c1.w*inv);
            *(uint4*)&Bc[br*64 + ((slot ^ (br & 7)))*8] = p;
        }
    }
    __syncthreads();

    f32x4 acc[2][4];
    #pragma unroll
    for (int m = 0; m < 2; ++m)
        #pragma unroll
        for (int n = 0; n < 4; ++n) {
            f32x4 z = {0.f, 0.f, 0.f, 0.f};
            acc[m][n] = z;
        }
    #pragma unroll
    for (int ks = 0; ks < 2; ++ks) {
        bf16x8 a[2], bv[4];
        #pragma unroll
        for (int mt = 0; mt < 2; ++mt) {
            const int jr = w*32 + mt*16 + l15;
            a[mt] = *(const bf16x8*)&Aw[jr*64 + (((ks*4+lg) ^ (jr & 7)))*8];
        }
        #pragma unroll
        for (int nt = 0; nt < 4; ++nt) {
            const int d = nt*16 + l15;
            bv[nt] = *(const bf16x8*)&Bc[d*64 + (((ks*4+lg) ^ (d & 7)))*8];
        }
        #pragma unroll
        for (int mt = 0; mt < 2; ++mt)
            #pragma unroll
            for (int nt = 0; nt < 4; ++nt)
                acc[mt][nt] = __builtin_amdgcn_mfma_f32_16x16x32_bf16(a[mt], bv[nt], acc[mt][nt], 0, 0, 0);
    }
    #pragma unroll
    for (int mt = 0; mt < 2; ++mt)
        #pragma unroll
        for (int nt = 0; nt < 4; ++nt)
            #pragma unroll
            for (int r = 0; r < 4; ++r) {
                const int j = j0 + w*32 + mt*16 + lg*4 + r;
                const int d = nt*16 + l15;
                Gt[(size_t)b*1048576 + (size_t)j*E_DIM + h*64 + d] = f2bf(acc[mt][nt][r]);
            }
}

// ---------------------------------------------------------------------------
extern "C" void kernel_launch(void* const* d_in, const int* in_sizes, int n_in,
                              void* d_out, int out_size, void* d_ws, size_t ws_size,
                              hipStream_t stream)
{
    const float* query = (const float*)d_in[0];
    const float* key   = (const float*)d_in[1];
    const float* value = (const float*)d_in[2];
    const unsigned char* mask = (const unsigned char*)d_in[3];
    const float* Wq  = (const float*)d_in[4];
    const float* bq  = (const float*)d_in[5];
    const float* Wk  = (const float*)d_in[6];
    const float* bk  = (const float*)d_in[7];
    const float* Wv  = (const float*)d_in[8];
    const float* bv_ = (const float*)d_in[9];
    const float* qla = (const float*)d_in[10];
    const float* qlb = (const float*)d_in[11];
    const float* kla = (const float*)d_in[12];
    const float* klb = (const float*)d_in[13];
    const float* vla = (const float*)d_in[14];
    const float* vlb = (const float*)d_in[15];
    const float* Wo  = (const float*)d_in[16];
    const float* bo  = (const float*)d_in[17];

    const size_t NEEDED = 118505472ULL;
    if (ws_size < NEEDED) {
        ws_sentinel<<<1, 256, 0, stream>>>((float*)d_out, (float)(ws_size >> 20));
        return;
    }

    char* ws = (char*)d_ws;
    unsigned short* Wt      = (unsigned short*)(ws + 0);          // 8 MB
    unsigned short* KT      = (unsigned short*)(ws + 8388608);    // 32 MB [b][1024][4096]
    unsigned short* VT      = (unsigned short*)(ws + 41943040);   // 32 MB
    float*          partial = (float*)(ws + 75497472);            // 16 MB (dead before qn)
    unsigned short* qn      = (unsigned short*)(ws + 75497472);   // 32 MB (overlays partial)
    unsigned short* Gt      = (unsigned short*)(ws + 109051904);  // 8 MB
    float*          colsum  = (float*)(ws + 117440512);           // 16 KB
    float*          ctx     = (float*)(ws + 117456896);           // 1 MB

    zero_colsum<<<16, 256, 0, stream>>>(colsum);
    prep_weights_t<<<dim3(32, 32, 4), 256, 0, stream>>>(Wq, Wk, Wv, Wo,
                                                        qla, qlb, kla, klb, vla, vlb, Wt);
    mfma_gemm<1,2,0><<<dim3(128, 8), 256, 0, stream>>>(key,   Wt + 1048576, bk, KT, mask, colsum);
    mfma_gemm<1,3,0><<<dim3(128, 8), 256, 0, stream>>>(value, Wt + 2097152, bv_, VT, nullptr, nullptr);
    context_mfma<<<dim3(16, HEADS, BATCH), 256, 0, stream>>>(KT, VT, mask, partial);
    reduce_ctx<<<256, 256, 0, stream>>>(partial, ctx);
    g_kernel<<<dim3(8, HEADS, BATCH), 256, 0, stream>>>(Wt + 3145728, ctx, colsum, Gt);
    mfma_gemm<1,1,0><<<dim3(128, 8), 256, 0, stream>>>(query, Wt, bq, qn, nullptr, nullptr);
    mfma_gemm<0,4,1><<<dim3(128, 8), 256, 0, stream>>>(qn, Gt, bo, (float*)d_out, nullptr, nullptr);
}